// Round 7
// baseline (1232.701 us; speedup 1.0000x reference)
//
#include <hip/hip_runtime.h>

#define NROWS 131072
#define DIM   128
#define FFD   512
#define TSTEPS 4
#define NBLK  512
#define CHUNK 128
#define NCHUNK 2   // NROWS / (NBLK*CHUNK)
#define NSLOT 16
#define SH    136  // stride for 128-wide bf16 LDS tiles (16B-aligned rows)

static_assert((long)NBLK * CHUNK * NCHUNK == NROWS, "grid/chunk mismatch");

typedef short          s8v   __attribute__((ext_vector_type(8)));
typedef float          f4v   __attribute__((ext_vector_type(4)));
typedef unsigned short u16x4 __attribute__((ext_vector_type(4)));

#define MFMA16(a,b,c) __builtin_amdgcn_mfma_f32_16x16x32_bf16((a),(b),(c),0,0,0)

__device__ __forceinline__ unsigned short f2bf(float f){
    unsigned u = __builtin_bit_cast(unsigned, f);
    u += 0x7FFFu + ((u >> 16) & 1u);   // round-to-nearest-even
    return (unsigned short)(u >> 16);
}
__device__ __forceinline__ float bf2f(unsigned short h){
    return __builtin_bit_cast(float, (unsigned)h << 16);
}
__device__ __forceinline__ f4v ntload4(const float* p){
    return __builtin_nontemporal_load((const f4v*)p);
}
__device__ __forceinline__ void ntstore4(float* p, f4v v){
    __builtin_nontemporal_store(v, (f4v*)p);
}

// ---------------------------------------------------------------------------
// Kernel A (t=0 only): LN1 (split bf16) of x_in, K/V proj, partial KtV -> slots.
// ---------------------------------------------------------------------------
__global__ __launch_bounds__(512, 2)
void kA(const float* __restrict__ x, const unsigned short* __restrict__ Kwp,
        const unsigned short* __restrict__ Vwp,
        const float* __restrict__ ga, const float* __restrict__ be,
        float* __restrict__ slots)
{
    __shared__ unsigned short hh[128*SH];
    __shared__ unsigned short hl[128*SH];
    __shared__ unsigned short KT[128*SH];
    __shared__ unsigned short VT[128*SH];
    const int tid  = threadIdx.x;
    const int wv   = tid >> 6, lane = tid & 63;
    const int quad = lane >> 4, l15 = lane & 15;
    const int lp   = lane >> 3, lr = lane & 7;
    const int myrow = wv*8 + lr;
    const int pc    = wv*16 + l15;

    s8v bfK[4], bfV[4];
    #pragma unroll
    for (int ks = 0; ks < 4; ++ks) {
        bfK[ks] = *(const s8v*)(Kwp + pc*DIM + ks*32 + quad*8);
        bfV[ks] = *(const s8v*)(Vwp + pc*DIM + ks*32 + quad*8);
    }

    f4v acc[8];
    #pragma unroll
    for (int i = 0; i < 8; ++i) acc[i] = (f4v){0.f,0.f,0.f,0.f};

    for (int ch = 0; ch < NCHUNK; ++ch) {
        const size_t r0 = ((size_t)blockIdx.x*NCHUNK + ch)*CHUNK;
        #pragma unroll
        for (int pp = 0; pp < 2; ++pp) {
            const int row = pp*64 + myrow;
            float v[16];
            #pragma unroll
            for (int j = 0; j < 4; ++j) {
                const f4v t = ntload4(x + (r0 + row)*DIM + lp*16 + j*4);
                v[j*4+0] = t[0]; v[j*4+1] = t[1]; v[j*4+2] = t[2]; v[j*4+3] = t[3];
            }
            float s = 0.f, q = 0.f;
            #pragma unroll
            for (int i = 0; i < 16; ++i) { s += v[i]; q += v[i]*v[i]; }
            #pragma unroll
            for (int o = 8; o < 64; o <<= 1) { s += __shfl_xor(s, o); q += __shfl_xor(q, o); }
            const float m  = s * (1.0f/128.0f);
            const float rs = rsqrtf(q * (1.0f/128.0f) - m*m + 1e-5f);
            unsigned short hi16[16], lo16[16];
            #pragma unroll
            for (int j = 0; j < 4; ++j) {
                const float4 g = *(const float4*)(ga + lp*16 + j*4);
                const float4 b = *(const float4*)(be + lp*16 + j*4);
                float hv0 = (v[j*4+0]-m)*rs*g.x + b.x;
                float hv1 = (v[j*4+1]-m)*rs*g.y + b.y;
                float hv2 = (v[j*4+2]-m)*rs*g.z + b.z;
                float hv3 = (v[j*4+3]-m)*rs*g.w + b.w;
                hi16[j*4+0] = f2bf(hv0); lo16[j*4+0] = f2bf(hv0 - bf2f(hi16[j*4+0]));
                hi16[j*4+1] = f2bf(hv1); lo16[j*4+1] = f2bf(hv1 - bf2f(hi16[j*4+1]));
                hi16[j*4+2] = f2bf(hv2); lo16[j*4+2] = f2bf(hv2 - bf2f(hi16[j*4+2]));
                hi16[j*4+3] = f2bf(hv3); lo16[j*4+3] = f2bf(hv3 - bf2f(hi16[j*4+3]));
            }
            #pragma unroll
            for (int j = 0; j < 2; ++j) {
                *(s8v*)&hh[row*SH + lp*16 + j*8] = *(const s8v*)&hi16[j*8];
                *(s8v*)&hl[row*SH + lp*16 + j*8] = *(const s8v*)&lo16[j*8];
            }
        }
        __syncthreads();
        #pragma unroll
        for (int p = 0; p < 2; ++p) {
            const s8v* bf = p ? bfV : bfK;
            unsigned short* T = p ? VT : KT;
            #pragma unroll
            for (int mt = 0; mt < 8; ++mt) {
                s8v ah[4], al[4];
                #pragma unroll
                for (int ks = 0; ks < 4; ++ks) {
                    ah[ks] = *(const s8v*)(&hh[(mt*16 + l15)*SH + ks*32 + quad*8]);
                    al[ks] = *(const s8v*)(&hl[(mt*16 + l15)*SH + ks*32 + quad*8]);
                }
                f4v c = {0.f,0.f,0.f,0.f};
                #pragma unroll
                for (int ks = 0; ks < 4; ++ks) c = MFMA16(ah[ks], bf[ks], c);
                #pragma unroll
                for (int ks = 0; ks < 4; ++ks) c = MFMA16(al[ks], bf[ks], c);
                u16x4 w4 = { f2bf(c[0]), f2bf(c[1]), f2bf(c[2]), f2bf(c[3]) };
                *(u16x4*)&T[pc*SH + mt*16 + quad*4] = w4;
            }
        }
        __syncthreads();
        #pragma unroll
        for (int ks = 0; ks < 4; ++ks) {
            const s8v af = *(const s8v*)(&KT[pc*SH + ks*32 + quad*8]);
            #pragma unroll
            for (int jt = 0; jt < 8; ++jt) {
                const s8v bfr = *(const s8v*)(&VT[(jt*16 + l15)*SH + ks*32 + quad*8]);
                acc[jt] = MFMA16(af, bfr, acc[jt]);
            }
        }
        __syncthreads();
    }
    float* S = slots + (size_t)(blockIdx.x & (NSLOT-1)) * 16384;
    #pragma unroll
    for (int jt = 0; jt < 8; ++jt) {
        const int i0 = wv*16 + quad*4;
        const int j  = jt*16 + l15;
        #pragma unroll
        for (int rg = 0; rg < 4; ++rg)
            atomicAdd(&S[(i0 + rg)*DIM + j], acc[jt][rg]);
    }
}

// Reduce NSLOT partial KtV matrices -> ktv (fp32, 128x128)
__global__ void kReduce(const float* __restrict__ slots, float* __restrict__ ktv)
{
    const int e = blockIdx.x*256 + threadIdx.x;
    float s = 0.f;
    #pragma unroll
    for (int b = 0; b < NSLOT; ++b) s += slots[(size_t)b*16384 + e];
    ktv[e] = s;
}

// M = Qw @ KtV (fp32), packed split bf16 as Mp/Ml[j][k]
__global__ void kBuildM(const float* __restrict__ Qw, const float* __restrict__ ktv,
                        unsigned short* __restrict__ Mp, unsigned short* __restrict__ Ml)
{
    const int idx = blockIdx.x*256 + threadIdx.x;
    const int j = idx >> 7, k = idx & 127;
    float s = 0.f;
    for (int i = 0; i < 128; ++i) s += Qw[k*128 + i] * ktv[i*128 + j];
    const unsigned short hi = f2bf(s);
    Mp[idx] = hi;
    Ml[idx] = f2bf(s - bf2f(hi));
}

// ---------------------------------------------------------------------------
// Kernel B-mid (t=0..2): transformer step on 2x128-row chunks; after storing
// x_new, FUSED next-timestep LN1 + K/V proj + partial KtV (replaces kA).
// KT/VT overlay the dead xb region (total LDS 136 KB).
// ---------------------------------------------------------------------------
__global__ __launch_bounds__(512, 2)
void kBmid(const float* __restrict__ xin, float* __restrict__ xout,
           const unsigned short* __restrict__ Mp, const unsigned short* __restrict__ Ml,
           const float* __restrict__ g1a, const float* __restrict__ b1a,
           const float* __restrict__ g2a, const float* __restrict__ b2a,
           const unsigned short* __restrict__ w1p, const float* __restrict__ fb1,
           const unsigned short* __restrict__ w2p, const float* __restrict__ fb2,
           const unsigned short* __restrict__ Kwp, const unsigned short* __restrict__ Vwp,
           float* __restrict__ slots)
{
    __shared__ __align__(16) char lds_raw[139264];
    unsigned short* const hs = (unsigned short*)lds_raw;            // 34816 B
    unsigned short* const hl = (unsigned short*)(lds_raw + 34816);  // 34816 B (fbuf)
    float*          const xb = (float*)(lds_raw + 69632);           // 67584 B
    unsigned short* const KT = (unsigned short*)(lds_raw + 69632);  // alias xb
    unsigned short* const VT = (unsigned short*)(lds_raw + 104448); // 34816 B
    unsigned short* const fbuf = hl;

    const int tid  = threadIdx.x;
    const int wv   = tid >> 6, lane = tid & 63;
    const int quad = lane >> 4, l15 = lane & 15;
    const int lp   = lane >> 3, lr = lane & 7;
    const int myrow = wv*8 + lr;
    const int cg    = wv*16 + l15;

    f4v acc[8];   // next-timestep KtV partials, persist across chunks
    #pragma unroll
    for (int i = 0; i < 8; ++i) acc[i] = (f4v){0.f,0.f,0.f,0.f};

    for (int ch = 0; ch < NCHUNK; ++ch) {
        const size_t r0 = ((size_t)blockIdx.x*NCHUNK + ch)*CHUNK;
        // --- stage x chunk into LDS ---
        #pragma unroll
        for (int i = 0; i < 8; ++i) {
            const int idx = tid + i*512;
            const int r = idx >> 5, c = (idx & 31)*4;
            const f4v t = ntload4(xin + (r0 + r)*DIM + c);
            *(f4v*)&xb[r*132 + c] = t;
        }
        __syncthreads();
        // --- LN1 (split), 2 passes ---
        #pragma unroll
        for (int pp = 0; pp < 2; ++pp) {
            const int row = pp*64 + myrow;
            float v[16];
            #pragma unroll
            for (int j = 0; j < 4; ++j)
                *(float4*)&v[j*4] = *(const float4*)&xb[row*132 + lp*16 + j*4];
            float s = 0.f, q = 0.f;
            #pragma unroll
            for (int i = 0; i < 16; ++i) { s += v[i]; q += v[i]*v[i]; }
            #pragma unroll
            for (int o = 8; o < 64; o <<= 1) { s += __shfl_xor(s, o); q += __shfl_xor(q, o); }
            const float m  = s * (1.0f/128.0f);
            const float rs = rsqrtf(q * (1.0f/128.0f) - m*m + 1e-5f);
            unsigned short hi16[16], lo16[16];
            #pragma unroll
            for (int j = 0; j < 4; ++j) {
                const float4 g = *(const float4*)(g1a + lp*16 + j*4);
                const float4 b = *(const float4*)(b1a + lp*16 + j*4);
                float hv0 = (v[j*4+0]-m)*rs*g.x + b.x;
                float hv1 = (v[j*4+1]-m)*rs*g.y + b.y;
                float hv2 = (v[j*4+2]-m)*rs*g.z + b.z;
                float hv3 = (v[j*4+3]-m)*rs*g.w + b.w;
                hi16[j*4+0] = f2bf(hv0); lo16[j*4+0] = f2bf(hv0 - bf2f(hi16[j*4+0]));
                hi16[j*4+1] = f2bf(hv1); lo16[j*4+1] = f2bf(hv1 - bf2f(hi16[j*4+1]));
                hi16[j*4+2] = f2bf(hv2); lo16[j*4+2] = f2bf(hv2 - bf2f(hi16[j*4+2]));
                hi16[j*4+3] = f2bf(hv3); lo16[j*4+3] = f2bf(hv3 - bf2f(hi16[j*4+3]));
            }
            #pragma unroll
            for (int j = 0; j < 2; ++j) {
                *(s8v*)&hs[row*SH + lp*16 + j*8] = *(const s8v*)&hi16[j*8];
                *(s8v*)&hl[row*SH + lp*16 + j*8] = *(const s8v*)&lo16[j*8];
            }
        }
        __syncthreads();
        // --- GEMM1: dx = h1 @ M (3-way split) ---
        {
            s8v bh[4], bl[4];
            #pragma unroll
            for (int ks = 0; ks < 4; ++ks) {
                bh[ks] = *(const s8v*)(Mp + cg*DIM + ks*32 + quad*8);
                bl[ks] = *(const s8v*)(Ml + cg*DIM + ks*32 + quad*8);
            }
            #pragma unroll
            for (int mt = 0; mt < 8; ++mt) {
                s8v ah[4], al[4];
                #pragma unroll
                for (int ks = 0; ks < 4; ++ks) {
                    ah[ks] = *(const s8v*)(&hs[(mt*16 + l15)*SH + ks*32 + quad*8]);
                    al[ks] = *(const s8v*)(&hl[(mt*16 + l15)*SH + ks*32 + quad*8]);
                }
                f4v c = {0.f,0.f,0.f,0.f};
                #pragma unroll
                for (int ks = 0; ks < 4; ++ks) c = MFMA16(ah[ks], bh[ks], c);
                #pragma unroll
                for (int ks = 0; ks < 4; ++ks) c = MFMA16(ah[ks], bl[ks], c);
                #pragma unroll
                for (int ks = 0; ks < 4; ++ks) c = MFMA16(al[ks], bh[ks], c);
                #pragma unroll
                for (int rg = 0; rg < 4; ++rg)
                    xb[(mt*16 + quad*4 + rg)*132 + cg] += c[rg];
            }
        }
        __syncthreads();
        // --- LN2 (hi only), 2 passes ---
        #pragma unroll
        for (int pp = 0; pp < 2; ++pp) {
            const int row = pp*64 + myrow;
            float v[16];
            #pragma unroll
            for (int j = 0; j < 4; ++j)
                *(float4*)&v[j*4] = *(const float4*)&xb[row*132 + lp*16 + j*4];
            float s = 0.f, q = 0.f;
            #pragma unroll
            for (int i = 0; i < 16; ++i) { s += v[i]; q += v[i]*v[i]; }
            #pragma unroll
            for (int o = 8; o < 64; o <<= 1) { s += __shfl_xor(s, o); q += __shfl_xor(q, o); }
            const float m  = s * (1.0f/128.0f);
            const float rs = rsqrtf(q * (1.0f/128.0f) - m*m + 1e-5f);
            unsigned short hi16[16];
            #pragma unroll
            for (int j = 0; j < 4; ++j) {
                const float4 g = *(const float4*)(g2a + lp*16 + j*4);
                const float4 b = *(const float4*)(b2a + lp*16 + j*4);
                hi16[j*4+0] = f2bf((v[j*4+0]-m)*rs*g.x + b.x);
                hi16[j*4+1] = f2bf((v[j*4+1]-m)*rs*g.y + b.y);
                hi16[j*4+2] = f2bf((v[j*4+2]-m)*rs*g.z + b.z);
                hi16[j*4+3] = f2bf((v[j*4+3]-m)*rs*g.w + b.w);
            }
            #pragma unroll
            for (int j = 0; j < 2; ++j)
                *(s8v*)&hs[row*SH + lp*16 + j*8] = *(const s8v*)&hi16[j*8];
        }
        __syncthreads();
        // --- FF: 4 quarters ---
        f4v dx2[8];
        #pragma unroll
        for (int i = 0; i < 8; ++i) dx2[i] = (f4v){0.f,0.f,0.f,0.f};
        #pragma unroll
        for (int qf = 0; qf < 4; ++qf) {
            const int ffc = qf*128 + cg;
            s8v wa[4];
            #pragma unroll
            for (int ks = 0; ks < 4; ++ks)
                wa[ks] = *(const s8v*)(w1p + ffc*DIM + ks*32 + quad*8);
            const float bias = fb1[ffc];
            #pragma unroll
            for (int mt = 0; mt < 8; ++mt) {
                s8v af[4];
                #pragma unroll
                for (int ks = 0; ks < 4; ++ks)
                    af[ks] = *(const s8v*)(&hs[(mt*16 + l15)*SH + ks*32 + quad*8]);
                f4v c = {0.f,0.f,0.f,0.f};
                #pragma unroll
                for (int ks = 0; ks < 4; ++ks) c = MFMA16(af[ks], wa[ks], c);
                #pragma unroll
                for (int rg = 0; rg < 4; ++rg) {
                    float vv = c[rg] + bias;
                    vv = vv > 0.f ? vv : 0.f;
                    fbuf[(mt*16 + quad*4 + rg)*SH + cg] = f2bf(vv);
                }
            }
            __syncthreads();
            s8v wb[4];
            #pragma unroll
            for (int ks = 0; ks < 4; ++ks)
                wb[ks] = *(const s8v*)(w2p + cg*FFD + qf*128 + ks*32 + quad*8);
            #pragma unroll
            for (int mt = 0; mt < 8; ++mt) {
                s8v af[4];
                #pragma unroll
                for (int ks = 0; ks < 4; ++ks)
                    af[ks] = *(const s8v*)(&fbuf[(mt*16 + l15)*SH + ks*32 + quad*8]);
                f4v c = dx2[mt];
                #pragma unroll
                for (int ks = 0; ks < 4; ++ks) c = MFMA16(af[ks], wb[ks], c);
                dx2[mt] = c;
            }
            __syncthreads();
        }
        // --- epilogue: xb += dx2 + b2 ---
        {
            const float bias = fb2[cg];
            #pragma unroll
            for (int mt = 0; mt < 8; ++mt)
                #pragma unroll
                for (int rg = 0; rg < 4; ++rg)
                    xb[(mt*16 + quad*4 + rg)*132 + cg] += dx2[mt][rg] + bias;
        }
        __syncthreads();
        // --- store x_new ---
        #pragma unroll
        for (int i = 0; i < 8; ++i) {
            const int idx = tid + i*512;
            const int r = idx >> 5, c = (idx & 31)*4;
            ntstore4(xout + (r0 + r)*DIM + c, *(const f4v*)&xb[r*132 + c]);
        }
        // ==== FUSED next-timestep LN1 + K/V proj + KtV (replaces kA) ====
        // LN1-split of x_new from xb into hs/hl (xb read-only here)
        #pragma unroll
        for (int pp = 0; pp < 2; ++pp) {
            const int row = pp*64 + myrow;
            float v[16];
            #pragma unroll
            for (int j = 0; j < 4; ++j)
                *(float4*)&v[j*4] = *(const float4*)&xb[row*132 + lp*16 + j*4];
            float s = 0.f, q = 0.f;
            #pragma unroll
            for (int i = 0; i < 16; ++i) { s += v[i]; q += v[i]*v[i]; }
            #pragma unroll
            for (int o = 8; o < 64; o <<= 1) { s += __shfl_xor(s, o); q += __shfl_xor(q, o); }
            const float m  = s * (1.0f/128.0f);
            const float rs = rsqrtf(q * (1.0f/128.0f) - m*m + 1e-5f);
            unsigned short hi16[16], lo16[16];
            #pragma unroll
            for (int j = 0; j < 4; ++j) {
                const float4 g = *(const float4*)(g1a + lp*16 + j*4);
                const float4 b = *(const float4*)(b1a + lp*16 + j*4);
                float hv0 = (v[j*4+0]-m)*rs*g.x + b.x;
                float hv1 = (v[j*4+1]-m)*rs*g.y + b.y;
                float hv2 = (v[j*4+2]-m)*rs*g.z + b.z;
                float hv3 = (v[j*4+3]-m)*rs*g.w + b.w;
                hi16[j*4+0] = f2bf(hv0); lo16[j*4+0] = f2bf(hv0 - bf2f(hi16[j*4+0]));
                hi16[j*4+1] = f2bf(hv1); lo16[j*4+1] = f2bf(hv1 - bf2f(hi16[j*4+1]));
                hi16[j*4+2] = f2bf(hv2); lo16[j*4+2] = f2bf(hv2 - bf2f(hi16[j*4+2]));
                hi16[j*4+3] = f2bf(hv3); lo16[j*4+3] = f2bf(hv3 - bf2f(hi16[j*4+3]));
            }
            #pragma unroll
            for (int j = 0; j < 2; ++j) {
                *(s8v*)&hs[row*SH + lp*16 + j*8] = *(const s8v*)&hi16[j*8];
                *(s8v*)&hl[row*SH + lp*16 + j*8] = *(const s8v*)&lo16[j*8];
            }
        }
        __syncthreads();   // xb dead after this point; KT/VT may overwrite it
        // K/V projections into KT/VT
        {
            s8v bfK[4], bfV[4];
            #pragma unroll
            for (int ks = 0; ks < 4; ++ks) {
                bfK[ks] = *(const s8v*)(Kwp + cg*DIM + ks*32 + quad*8);
                bfV[ks] = *(const s8v*)(Vwp + cg*DIM + ks*32 + quad*8);
            }
            #pragma unroll
            for (int p = 0; p < 2; ++p) {
                const s8v* bf = p ? bfV : bfK;
                unsigned short* T = p ? VT : KT;
                #pragma unroll
                for (int mt = 0; mt < 8; ++mt) {
                    s8v ah[4], al[4];
                    #pragma unroll
                    for (int ks = 0; ks < 4; ++ks) {
                        ah[ks] = *(const s8v*)(&hs[(mt*16 + l15)*SH + ks*32 + quad*8]);
                        al[ks] = *(const s8v*)(&hl[(mt*16 + l15)*SH + ks*32 + quad*8]);
                    }
                    f4v c = {0.f,0.f,0.f,0.f};
                    #pragma unroll
                    for (int ks = 0; ks < 4; ++ks) c = MFMA16(ah[ks], bf[ks], c);
                    #pragma unroll
                    for (int ks = 0; ks < 4; ++ks) c = MFMA16(al[ks], bf[ks], c);
                    u16x4 w4 = { f2bf(c[0]), f2bf(c[1]), f2bf(c[2]), f2bf(c[3]) };
                    *(u16x4*)&T[cg*SH + mt*16 + quad*4] = w4;
                }
            }
        }
        __syncthreads();
        // KtV accumulation
        #pragma unroll
        for (int ks = 0; ks < 4; ++ks) {
            const s8v af = *(const s8v*)(&KT[cg*SH + ks*32 + quad*8]);
            #pragma unroll
            for (int jt = 0; jt < 8; ++jt) {
                const s8v bfr = *(const s8v*)(&VT[(jt*16 + l15)*SH + ks*32 + quad*8]);
                acc[jt] = MFMA16(af, bfr, acc[jt]);
            }
        }
        __syncthreads();   // KT/VT dead; next chunk may restage xb
    }
    // --- accumulate next-timestep partial KtV into slots ---
    float* S = slots + (size_t)(blockIdx.x & (NSLOT-1)) * 16384;
    #pragma unroll
    for (int jt = 0; jt < 8; ++jt) {
        const int i0 = wv*16 + quad*4;
        const int j  = jt*16 + l15;
        #pragma unroll
        for (int rg = 0; rg < 4; ++rg)
            atomicAdd(&S[(i0 + rg)*DIM + j], acc[jt][rg]);
    }
}

// ---------------------------------------------------------------------------
// Kernel B-last (t=3): transformer step; instead of storing x_new, FUSED
// final projection out = x_new @ out_w + out_b (replaces kF).
// ---------------------------------------------------------------------------
__global__ __launch_bounds__(512, 2)
void kBlast(const float* __restrict__ xin,
            const unsigned short* __restrict__ Mp, const unsigned short* __restrict__ Ml,
            const float* __restrict__ g1a, const float* __restrict__ b1a,
            const float* __restrict__ g2a, const float* __restrict__ b2a,
            const unsigned short* __restrict__ w1p, const float* __restrict__ fb1,
            const unsigned short* __restrict__ w2p, const float* __restrict__ fb2,
            const unsigned short* __restrict__ Owp, const float* __restrict__ ob,
            float* __restrict__ out)
{
    __shared__ unsigned short hs[128*SH];
    __shared__ unsigned short fbuf[128*SH];
    __shared__ float          xb[128*132];
    unsigned short* const hl = fbuf;
    const int tid  = threadIdx.x;
    const int wv   = tid >> 6, lane = tid & 63;
    const int quad = lane >> 4, l15 = lane & 15;
    const int lp   = lane >> 3, lr = lane & 7;
    const int myrow = wv*8 + lr;
    const int cg    = wv*16 + l15;

    for (int ch = 0; ch < NCHUNK; ++ch) {
        const size_t r0 = ((size_t)blockIdx.x*NCHUNK + ch)*CHUNK;
        #pragma unroll
        for (int i = 0; i < 8; ++i) {
            const int idx = tid + i*512;
            const int r = idx >> 5, c = (idx & 31)*4;
            const f4v t = ntload4(xin + (r0 + r)*DIM + c);
            *(f4v*)&xb[r*132 + c] = t;
        }
        __syncthreads();
        // --- LN1 (split) ---
        #pragma unroll
        for (int pp = 0; pp < 2; ++pp) {
            const int row = pp*64 + myrow;
            float v[16];
            #pragma unroll
            for (int j = 0; j < 4; ++j)
                *(float4*)&v[j*4] = *(const float4*)&xb[row*132 + lp*16 + j*4];
            float s = 0.f, q = 0.f;
            #pragma unroll
            for (int i = 0; i < 16; ++i) { s += v[i]; q += v[i]*v[i]; }
            #pragma unroll
            for (int o = 8; o < 64; o <<= 1) { s += __shfl_xor(s, o); q += __shfl_xor(q, o); }
            const float m  = s * (1.0f/128.0f);
            const float rs = rsqrtf(q * (1.0f/128.0f) - m*m + 1e-5f);
            unsigned short hi16[16], lo16[16];
            #pragma unroll
            for (int j = 0; j < 4; ++j) {
                const float4 g = *(const float4*)(g1a + lp*16 + j*4);
                const float4 b = *(const float4*)(b1a + lp*16 + j*4);
                float hv0 = (v[j*4+0]-m)*rs*g.x + b.x;
                float hv1 = (v[j*4+1]-m)*rs*g.y + b.y;
                float hv2 = (v[j*4+2]-m)*rs*g.z + b.z;
                float hv3 = (v[j*4+3]-m)*rs*g.w + b.w;
                hi16[j*4+0] = f2bf(hv0); lo16[j*4+0] = f2bf(hv0 - bf2f(hi16[j*4+0]));
                hi16[j*4+1] = f2bf(hv1); lo16[j*4+1] = f2bf(hv1 - bf2f(hi16[j*4+1]));
                hi16[j*4+2] = f2bf(hv2); lo16[j*4+2] = f2bf(hv2 - bf2f(hi16[j*4+2]));
                hi16[j*4+3] = f2bf(hv3); lo16[j*4+3] = f2bf(hv3 - bf2f(hi16[j*4+3]));
            }
            #pragma unroll
            for (int j = 0; j < 2; ++j) {
                *(s8v*)&hs[row*SH + lp*16 + j*8] = *(const s8v*)&hi16[j*8];
                *(s8v*)&hl[row*SH + lp*16 + j*8] = *(const s8v*)&lo16[j*8];
            }
        }
        __syncthreads();
        // --- GEMM1 ---
        {
            s8v bh[4], bl[4];
            #pragma unroll
            for (int ks = 0; ks < 4; ++ks) {
                bh[ks] = *(const s8v*)(Mp + cg*DIM + ks*32 + quad*8);
                bl[ks] = *(const s8v*)(Ml + cg*DIM + ks*32 + quad*8);
            }
            #pragma unroll
            for (int mt = 0; mt < 8; ++mt) {
                s8v ah[4], al[4];
                #pragma unroll
                for (int ks = 0; ks < 4; ++ks) {
                    ah[ks] = *(const s8v*)(&hs[(mt*16 + l15)*SH + ks*32 + quad*8]);
                    al[ks] = *(const s8v*)(&hl[(mt*16 + l15)*SH + ks*32 + quad*8]);
                }
                f4v c = {0.f,0.f,0.f,0.f};
                #pragma unroll
                for (int ks = 0; ks < 4; ++ks) c = MFMA16(ah[ks], bh[ks], c);
                #pragma unroll
                for (int ks = 0; ks < 4; ++ks) c = MFMA16(ah[ks], bl[ks], c);
                #pragma unroll
                for (int ks = 0; ks < 4; ++ks) c = MFMA16(al[ks], bh[ks], c);
                #pragma unroll
                for (int rg = 0; rg < 4; ++rg)
                    xb[(mt*16 + quad*4 + rg)*132 + cg] += c[rg];
            }
        }
        __syncthreads();
        // --- LN2 ---
        #pragma unroll
        for (int pp = 0; pp < 2; ++pp) {
            const int row = pp*64 + myrow;
            float v[16];
            #pragma unroll
            for (int j = 0; j < 4; ++j)
                *(float4*)&v[j*4] = *(const float4*)&xb[row*132 + lp*16 + j*4];
            float s = 0.f, q = 0.f;
            #pragma unroll
            for (int i = 0; i < 16; ++i) { s += v[i]; q += v[i]*v[i]; }
            #pragma unroll
            for (int o = 8; o < 64; o <<= 1) { s += __shfl_xor(s, o); q += __shfl_xor(q, o); }
            const float m  = s * (1.0f/128.0f);
            const float rs = rsqrtf(q * (1.0f/128.0f) - m*m + 1e-5f);
            unsigned short hi16[16];
            #pragma unroll
            for (int j = 0; j < 4; ++j) {
                const float4 g = *(const float4*)(g2a + lp*16 + j*4);
                const float4 b = *(const float4*)(b2a + lp*16 + j*4);
                hi16[j*4+0] = f2bf((v[j*4+0]-m)*rs*g.x + b.x);
                hi16[j*4+1] = f2bf((v[j*4+1]-m)*rs*g.y + b.y);
                hi16[j*4+2] = f2bf((v[j*4+2]-m)*rs*g.z + b.z);
                hi16[j*4+3] = f2bf((v[j*4+3]-m)*rs*g.w + b.w);
            }
            #pragma unroll
            for (int j = 0; j < 2; ++j)
                *(s8v*)&hs[row*SH + lp*16 + j*8] = *(const s8v*)&hi16[j*8];
        }
        __syncthreads();
        // --- FF ---
        f4v dx2[8];
        #pragma unroll
        for (int i = 0; i < 8; ++i) dx2[i] = (f4v){0.f,0.f,0.f,0.f};
        #pragma unroll
        for (int qf = 0; qf < 4; ++qf) {
            const int ffc = qf*128 + cg;
            s8v wa[4];
            #pragma unroll
            for (int ks = 0; ks < 4; ++ks)
                wa[ks] = *(const s8v*)(w1p + ffc*DIM + ks*32 + quad*8);
            const float bias = fb1[ffc];
            #pragma unroll
            for (int mt = 0; mt < 8; ++mt) {
                s8v af[4];
                #pragma unroll
                for (int ks = 0; ks < 4; ++ks)
                    af[ks] = *(const s8v*)(&hs[(mt*16 + l15)*SH + ks*32 + quad*8]);
                f4v c = {0.f,0.f,0.f,0.f};
                #pragma unroll
                for (int ks = 0; ks < 4; ++ks) c = MFMA16(af[ks], wa[ks], c);
                #pragma unroll
                for (int rg = 0; rg < 4; ++rg) {
                    float vv = c[rg] + bias;
                    vv = vv > 0.f ? vv : 0.f;
                    fbuf[(mt*16 + quad*4 + rg)*SH + cg] = f2bf(vv);
                }
            }
            __syncthreads();
            s8v wb[4];
            #pragma unroll
            for (int ks = 0; ks < 4; ++ks)
                wb[ks] = *(const s8v*)(w2p + cg*FFD + qf*128 + ks*32 + quad*8);
            #pragma unroll
            for (int mt = 0; mt < 8; ++mt) {
                s8v af[4];
                #pragma unroll
                for (int ks = 0; ks < 4; ++ks)
                    af[ks] = *(const s8v*)(&fbuf[(mt*16 + l15)*SH + ks*32 + quad*8]);
                f4v c = dx2[mt];
                #pragma unroll
                for (int ks = 0; ks < 4; ++ks) c = MFMA16(af[ks], wb[ks], c);
                dx2[mt] = c;
            }
            __syncthreads();
        }
        // --- epilogue: xb += dx2 + b2  (x_new, never stored) ---
        {
            const float bias = fb2[cg];
            #pragma unroll
            for (int mt = 0; mt < 8; ++mt)
                #pragma unroll
                for (int rg = 0; rg < 4; ++rg)
                    xb[(mt*16 + quad*4 + rg)*132 + cg] += dx2[mt][rg] + bias;
        }
        __syncthreads();
        // ==== FUSED final projection: out = x_new @ Ow + ob (replaces kF) ====
        // split x_new (raw, no LN) into hs/hl
        #pragma unroll
        for (int i = 0; i < 8; ++i) {
            const int idx = tid + i*512;
            const int r = idx >> 5, c = (idx & 31)*4;
            const float4 v = *(const float4*)&xb[r*132 + c];
            const unsigned short h0 = f2bf(v.x), h1 = f2bf(v.y),
                                 h2 = f2bf(v.z), h3 = f2bf(v.w);
            u16x4 w4 = { h0, h1, h2, h3 };
            u16x4 l4 = { f2bf(v.x - bf2f(h0)), f2bf(v.y - bf2f(h1)),
                         f2bf(v.z - bf2f(h2)), f2bf(v.w - bf2f(h3)) };
            *(u16x4*)&hs[r*SH + c] = w4;
            *(u16x4*)&hl[r*SH + c] = l4;
        }
        __syncthreads();   // xb dead; reused for O-proj output staging
        {
            s8v bfO[4];
            #pragma unroll
            for (int ks = 0; ks < 4; ++ks)
                bfO[ks] = *(const s8v*)(Owp + cg*DIM + ks*32 + quad*8);
            const float bias = ob[cg];
            #pragma unroll
            for (int mt = 0; mt < 8; ++mt) {
                s8v ah[4], al[4];
                #pragma unroll
                for (int ks = 0; ks < 4; ++ks) {
                    ah[ks] = *(const s8v*)(&hs[(mt*16 + l15)*SH + ks*32 + quad*8]);
                    al[ks] = *(const s8v*)(&hl[(mt*16 + l15)*SH + ks*32 + quad*8]);
                }
                f4v c = {0.f,0.f,0.f,0.f};
                #pragma unroll
                for (int ks = 0; ks < 4; ++ks) c = MFMA16(ah[ks], bfO[ks], c);
                #pragma unroll
                for (int ks = 0; ks < 4; ++ks) c = MFMA16(al[ks], bfO[ks], c);
                #pragma unroll
                for (int rg = 0; rg < 4; ++rg)
                    xb[(mt*16 + quad*4 + rg)*132 + cg] = c[rg] + bias;
            }
        }
        __syncthreads();
        #pragma unroll
        for (int i = 0; i < 8; ++i) {
            const int idx = tid + i*512;
            const int r = idx >> 5, c = (idx & 31)*4;
            ntstore4(out + (r0 + r)*DIM + c, *(const f4v*)&xb[r*132 + c]);
        }
        __syncthreads();
    }
}

// Pack weights to bf16, transposed to B-operand-friendly [n][k] layout.
__global__ void kPack(const float* __restrict__ Kw, const float* __restrict__ Vw,
                      const float* __restrict__ Ow, const float* __restrict__ w1,
                      const float* __restrict__ w2,
                      unsigned short* __restrict__ Kwp, unsigned short* __restrict__ Vwp,
                      unsigned short* __restrict__ Owp, unsigned short* __restrict__ w1p,
                      unsigned short* __restrict__ w2p)
{
    const int t = blockIdx.x*256 + threadIdx.x;  // 147456 total
    if (t < 16384) {
        const int n = t >> 7, k = t & 127;
        Kwp[t] = f2bf(Kw[k*128 + n]);
        Vwp[t] = f2bf(Vw[k*128 + n]);
        Owp[t] = f2bf(Ow[k*128 + n]);
    } else if (t < 16384 + 65536) {
        const int u = t - 16384;
        const int n = u >> 7, k = u & 127;
        w1p[u] = f2bf(w1[k*FFD + n]);
    } else {
        const int u = t - 16384 - 65536;
        const int n = u >> 9, k = u & 511;
        w2p[u] = f2bf(w2[k*DIM + n]);
    }
}

extern "C" void kernel_launch(void* const* d_in, const int* in_sizes, int n_in,
                              void* d_out, int out_size, void* d_ws, size_t ws_size,
                              hipStream_t stream)
{
    (void)in_sizes; (void)n_in; (void)out_size; (void)ws_size;
    const float* x_in = (const float*)d_in[0];
    const float* Kw   = (const float*)d_in[1];
    const float* Qw   = (const float*)d_in[2];
    const float* Vw   = (const float*)d_in[3];
    const float* ln1g = (const float*)d_in[4];
    const float* ln1b = (const float*)d_in[5];
    const float* ln2g = (const float*)d_in[6];
    const float* ln2b = (const float*)d_in[7];
    const float* w1   = (const float*)d_in[8];
    const float* b1   = (const float*)d_in[9];
    const float* w2   = (const float*)d_in[10];
    const float* b2   = (const float*)d_in[11];
    const float* Ow   = (const float*)d_in[12];
    const float* ob   = (const float*)d_in[13];

    // Workspace (~1.5 MiB single-copy layout).
    char* p = (char*)d_ws;
    float* slots        = (float*)p;          p += (size_t)NSLOT*16384*4;
    float* ktv          = (float*)p;          p += 16384*4;
    unsigned short* Kwp = (unsigned short*)p; p += 16384*2;
    unsigned short* Vwp = (unsigned short*)p; p += 16384*2;
    unsigned short* Owp = (unsigned short*)p; p += 16384*2;
    unsigned short* w1p = (unsigned short*)p; p += 65536*2;
    unsigned short* w2p = (unsigned short*)p; p += 65536*2;
    unsigned short* Mp  = (unsigned short*)p; p += 16384*2;
    unsigned short* Ml  = (unsigned short*)p; p += 16384*2;

    float* X = (float*)d_out;   // working buffer == output buffer

    kPack<<<576, 256, 0, stream>>>(Kw, Vw, Ow, w1, w2, Kwp, Vwp, Owp, w1p, w2p);

    (void)hipMemsetAsync(slots, 0, (size_t)NSLOT*16384*4, stream);
    kA<<<NBLK, 512, 0, stream>>>(x_in, Kwp, Vwp, ln1g, ln1b, slots);

    const float* src = x_in;
    for (int t = 0; t < TSTEPS-1; ++t) {
        kReduce<<<64, 256, 0, stream>>>(slots, ktv);
        kBuildM<<<64, 256, 0, stream>>>(Qw, ktv, Mp, Ml);
        (void)hipMemsetAsync(slots, 0, (size_t)NSLOT*16384*4, stream);
        kBmid<<<NBLK, 512, 0, stream>>>(src, X, Mp, Ml, ln1g, ln1b, ln2g, ln2b,
                                        w1p, b1, w2p, b2, Kwp, Vwp, slots);
        src = X;
    }
    kReduce<<<64, 256, 0, stream>>>(slots, ktv);
    kBuildM<<<64, 256, 0, stream>>>(Qw, ktv, Mp, Ml);
    kBlast<<<NBLK, 512, 0, stream>>>(src, Mp, Ml, ln1g, ln1b, ln2g, ln2b,
                                     w1p, b1, w2p, b2, Owp, ob, (float*)d_out);
}

// Round 9
// 1185.829 us; speedup vs baseline: 1.0395x; 1.0395x over previous
//
#include <hip/hip_runtime.h>

#define NROWS 131072
#define DIM   128
#define FFD   512
#define TSTEPS 4
#define NBLK  512
#define CHUNK 128
#define NCHUNK 2   // NROWS / (NBLK*CHUNK)
#define NSLOT 16
#define SH    136  // stride for 128-wide bf16 LDS tiles (16B-aligned rows)

static_assert((long)NBLK * CHUNK * NCHUNK == NROWS, "grid/chunk mismatch");

typedef short          s8v   __attribute__((ext_vector_type(8)));
typedef float          f4v   __attribute__((ext_vector_type(4)));
typedef unsigned short u16x4 __attribute__((ext_vector_type(4)));

#define MFMA16(a,b,c) __builtin_amdgcn_mfma_f32_16x16x32_bf16((a),(b),(c),0,0,0)

__device__ __forceinline__ unsigned short f2bf(float f){
    unsigned u = __builtin_bit_cast(unsigned, f);
    u += 0x7FFFu + ((u >> 16) & 1u);   // round-to-nearest-even
    return (unsigned short)(u >> 16);
}
__device__ __forceinline__ float bf2f(unsigned short h){
    return __builtin_bit_cast(float, (unsigned)h << 16);
}
__device__ __forceinline__ f4v ntload4(const float* p){
    return __builtin_nontemporal_load((const f4v*)p);
}
__device__ __forceinline__ void ntstore4(float* p, f4v v){
    __builtin_nontemporal_store(v, (f4v*)p);
}

// ---------------------------------------------------------------------------
// Kernel A: LN1 (split bf16), K/V projections, per-block partial KtV -> slots.
// CHUNK=128, 2 chunks/block; K/V weight fragments hoisted (loaded once/block).
// ---------------------------------------------------------------------------
__global__ __launch_bounds__(512, 2)
void kA(const float* __restrict__ x, const unsigned short* __restrict__ Kwp,
        const unsigned short* __restrict__ Vwp,
        const float* __restrict__ ga, const float* __restrict__ be,
        float* __restrict__ slots)
{
    __shared__ unsigned short hh[128*SH];
    __shared__ unsigned short hl[128*SH];
    __shared__ unsigned short KT[128*SH];
    __shared__ unsigned short VT[128*SH];
    const int tid  = threadIdx.x;
    const int wv   = tid >> 6, lane = tid & 63;
    const int quad = lane >> 4, l15 = lane & 15;
    const int lp   = lane >> 3, lr = lane & 7;
    const int myrow = wv*8 + lr;
    const int pc    = wv*16 + l15;

    s8v bfK[4], bfV[4];
    #pragma unroll
    for (int ks = 0; ks < 4; ++ks) {
        bfK[ks] = *(const s8v*)(Kwp + pc*DIM + ks*32 + quad*8);
        bfV[ks] = *(const s8v*)(Vwp + pc*DIM + ks*32 + quad*8);
    }

    f4v acc[8];
    #pragma unroll
    for (int i = 0; i < 8; ++i) acc[i] = (f4v){0.f,0.f,0.f,0.f};

    for (int ch = 0; ch < NCHUNK; ++ch) {
        const size_t r0 = ((size_t)blockIdx.x*NCHUNK + ch)*CHUNK;
        #pragma unroll
        for (int pp = 0; pp < 2; ++pp) {
            const int row = pp*64 + myrow;
            float v[16];
            #pragma unroll
            for (int j = 0; j < 4; ++j) {
                const f4v t = ntload4(x + (r0 + row)*DIM + lp*16 + j*4);
                v[j*4+0] = t[0]; v[j*4+1] = t[1]; v[j*4+2] = t[2]; v[j*4+3] = t[3];
            }
            float s = 0.f, q = 0.f;
            #pragma unroll
            for (int i = 0; i < 16; ++i) { s += v[i]; q += v[i]*v[i]; }
            #pragma unroll
            for (int o = 8; o < 64; o <<= 1) { s += __shfl_xor(s, o); q += __shfl_xor(q, o); }
            const float m  = s * (1.0f/128.0f);
            const float rs = rsqrtf(q * (1.0f/128.0f) - m*m + 1e-5f);
            unsigned short hi16[16], lo16[16];
            #pragma unroll
            for (int j = 0; j < 4; ++j) {
                const float4 g = *(const float4*)(ga + lp*16 + j*4);
                const float4 b = *(const float4*)(be + lp*16 + j*4);
                float hv0 = (v[j*4+0]-m)*rs*g.x + b.x;
                float hv1 = (v[j*4+1]-m)*rs*g.y + b.y;
                float hv2 = (v[j*4+2]-m)*rs*g.z + b.z;
                float hv3 = (v[j*4+3]-m)*rs*g.w + b.w;
                hi16[j*4+0] = f2bf(hv0); lo16[j*4+0] = f2bf(hv0 - bf2f(hi16[j*4+0]));
                hi16[j*4+1] = f2bf(hv1); lo16[j*4+1] = f2bf(hv1 - bf2f(hi16[j*4+1]));
                hi16[j*4+2] = f2bf(hv2); lo16[j*4+2] = f2bf(hv2 - bf2f(hi16[j*4+2]));
                hi16[j*4+3] = f2bf(hv3); lo16[j*4+3] = f2bf(hv3 - bf2f(hi16[j*4+3]));
            }
            #pragma unroll
            for (int j = 0; j < 2; ++j) {
                *(s8v*)&hh[row*SH + lp*16 + j*8] = *(const s8v*)&hi16[j*8];
                *(s8v*)&hl[row*SH + lp*16 + j*8] = *(const s8v*)&lo16[j*8];
            }
        }
        __syncthreads();
        #pragma unroll
        for (int p = 0; p < 2; ++p) {
            const s8v* bf = p ? bfV : bfK;
            unsigned short* T = p ? VT : KT;
            #pragma unroll
            for (int mt = 0; mt < 8; ++mt) {
                s8v ah[4], al[4];
                #pragma unroll
                for (int ks = 0; ks < 4; ++ks) {
                    ah[ks] = *(const s8v*)(&hh[(mt*16 + l15)*SH + ks*32 + quad*8]);
                    al[ks] = *(const s8v*)(&hl[(mt*16 + l15)*SH + ks*32 + quad*8]);
                }
                f4v c = {0.f,0.f,0.f,0.f};
                #pragma unroll
                for (int ks = 0; ks < 4; ++ks) c = MFMA16(ah[ks], bf[ks], c);
                #pragma unroll
                for (int ks = 0; ks < 4; ++ks) c = MFMA16(al[ks], bf[ks], c);
                u16x4 w4 = { f2bf(c[0]), f2bf(c[1]), f2bf(c[2]), f2bf(c[3]) };
                *(u16x4*)&T[pc*SH + mt*16 + quad*4] = w4;
            }
        }
        __syncthreads();
        #pragma unroll
        for (int ks = 0; ks < 4; ++ks) {
            const s8v af = *(const s8v*)(&KT[pc*SH + ks*32 + quad*8]);
            #pragma unroll
            for (int jt = 0; jt < 8; ++jt) {
                const s8v bfr = *(const s8v*)(&VT[(jt*16 + l15)*SH + ks*32 + quad*8]);
                acc[jt] = MFMA16(af, bfr, acc[jt]);
            }
        }
        __syncthreads();
    }
    float* S = slots + (size_t)(blockIdx.x & (NSLOT-1)) * 16384;
    #pragma unroll
    for (int jt = 0; jt < 8; ++jt) {
        const int i0 = wv*16 + quad*4;
        const int j  = jt*16 + l15;
        #pragma unroll
        for (int rg = 0; rg < 4; ++rg)
            atomicAdd(&S[(i0 + rg)*DIM + j], acc[jt][rg]);
    }
}

// Reduce NSLOT partial KtV matrices -> ktv (fp32, 128x128)
__global__ void kReduce(const float* __restrict__ slots, float* __restrict__ ktv)
{
    const int e = blockIdx.x*256 + threadIdx.x;
    float s = 0.f;
    #pragma unroll
    for (int b = 0; b < NSLOT; ++b) s += slots[(size_t)b*16384 + e];
    ktv[e] = s;
}

// M = Qw @ KtV (fp32), packed split bf16 as Mp/Ml[j][k]
__global__ void kBuildM(const float* __restrict__ Qw, const float* __restrict__ ktv,
                        unsigned short* __restrict__ Mp, unsigned short* __restrict__ Ml)
{
    const int idx = blockIdx.x*256 + threadIdx.x;
    const int j = idx >> 7, k = idx & 127;
    float s = 0.f;
    for (int i = 0; i < 128; ++i) s += Qw[k*128 + i] * ktv[i*128 + j];
    const unsigned short hi = f2bf(s);
    Mp[idx] = hi;
    Ml[idx] = f2bf(s - bf2f(hi));
}

// ---------------------------------------------------------------------------
// Kernel B: x += h1 @ M ; LN2 ; x += relu(h2@w1+b1)@w2 + b2   (in-place safe)
// CHUNK=128, 2 chunks/block. Mp/Ml hoisted + w1 (GEMM2a) fragments hoisted
// (64 VGPRs, ~170 total — safely under the 256 cap). w2 fragments stay
// in-loop (conservative after R8's post-timing failure at ~230 VGPRs).
// ---------------------------------------------------------------------------
__global__ __launch_bounds__(512, 2)
void kB(const float* __restrict__ xin, float* __restrict__ xout,
        const unsigned short* __restrict__ Mp, const unsigned short* __restrict__ Ml,
        const float* __restrict__ g1a, const float* __restrict__ b1a,
        const float* __restrict__ g2a, const float* __restrict__ b2a,
        const unsigned short* __restrict__ w1p, const float* __restrict__ fb1,
        const unsigned short* __restrict__ w2p, const float* __restrict__ fb2)
{
    __shared__ float          xb[128*132];  // fp32 residual tile (67.6 KB)
    __shared__ unsigned short hs[128*SH];   // bf16 LN output hi   (34.8 KB)
    __shared__ unsigned short fbuf[128*SH]; // relu(ff) / h1-lo    (34.8 KB)
    unsigned short* const hl = fbuf;
    const int tid  = threadIdx.x;
    const int wv   = tid >> 6, lane = tid & 63;
    const int quad = lane >> 4, l15 = lane & 15;
    const int lp   = lane >> 3, lr = lane & 7;
    const int myrow = wv*8 + lr;
    const int cg    = wv*16 + l15;

    // --- hoisted fragments: loaded once per block ---
    s8v bh[4], bl[4];
    #pragma unroll
    for (int ks = 0; ks < 4; ++ks) {
        bh[ks] = *(const s8v*)(Mp + cg*DIM + ks*32 + quad*8);
        bl[ks] = *(const s8v*)(Ml + cg*DIM + ks*32 + quad*8);
    }
    s8v wa[4][4];
    float b1r[4];
    #pragma unroll
    for (int qf = 0; qf < 4; ++qf) {
        const int ffc = qf*128 + cg;
        #pragma unroll
        for (int ks = 0; ks < 4; ++ks)
            wa[qf][ks] = *(const s8v*)(w1p + ffc*DIM + ks*32 + quad*8);
        b1r[qf] = fb1[ffc];
    }

    for (int ch = 0; ch < NCHUNK; ++ch) {
        const size_t r0 = ((size_t)blockIdx.x*NCHUNK + ch)*CHUNK;
        // --- stage x chunk into LDS ---
        #pragma unroll
        for (int i = 0; i < 8; ++i) {
            const int idx = tid + i*512;
            const int r = idx >> 5, c = (idx & 31)*4;
            const f4v t = ntload4(xin + (r0 + r)*DIM + c);
            *(f4v*)&xb[r*132 + c] = t;
        }
        __syncthreads();
        // --- LN1 (split), 2 passes of 64 rows ---
        #pragma unroll
        for (int pp = 0; pp < 2; ++pp) {
            const int row = pp*64 + myrow;
            float v[16];
            #pragma unroll
            for (int j = 0; j < 4; ++j)
                *(float4*)&v[j*4] = *(const float4*)&xb[row*132 + lp*16 + j*4];
            float s = 0.f, q = 0.f;
            #pragma unroll
            for (int i = 0; i < 16; ++i) { s += v[i]; q += v[i]*v[i]; }
            #pragma unroll
            for (int o = 8; o < 64; o <<= 1) { s += __shfl_xor(s, o); q += __shfl_xor(q, o); }
            const float m  = s * (1.0f/128.0f);
            const float rs = rsqrtf(q * (1.0f/128.0f) - m*m + 1e-5f);
            unsigned short hi16[16], lo16[16];
            #pragma unroll
            for (int j = 0; j < 4; ++j) {
                const float4 g = *(const float4*)(g1a + lp*16 + j*4);
                const float4 b = *(const float4*)(b1a + lp*16 + j*4);
                float hv0 = (v[j*4+0]-m)*rs*g.x + b.x;
                float hv1 = (v[j*4+1]-m)*rs*g.y + b.y;
                float hv2 = (v[j*4+2]-m)*rs*g.z + b.z;
                float hv3 = (v[j*4+3]-m)*rs*g.w + b.w;
                hi16[j*4+0] = f2bf(hv0); lo16[j*4+0] = f2bf(hv0 - bf2f(hi16[j*4+0]));
                hi16[j*4+1] = f2bf(hv1); lo16[j*4+1] = f2bf(hv1 - bf2f(hi16[j*4+1]));
                hi16[j*4+2] = f2bf(hv2); lo16[j*4+2] = f2bf(hv2 - bf2f(hi16[j*4+2]));
                hi16[j*4+3] = f2bf(hv3); lo16[j*4+3] = f2bf(hv3 - bf2f(hi16[j*4+3]));
            }
            #pragma unroll
            for (int j = 0; j < 2; ++j) {
                *(s8v*)&hs[row*SH + lp*16 + j*8] = *(const s8v*)&hi16[j*8];
                *(s8v*)&hl[row*SH + lp*16 + j*8] = *(const s8v*)&lo16[j*8];
            }
        }
        __syncthreads();
        // --- GEMM1: dx = h1 @ M (3-way split), M fragments from registers ---
        #pragma unroll
        for (int mt = 0; mt < 8; ++mt) {
            s8v ah[4], al[4];
            #pragma unroll
            for (int ks = 0; ks < 4; ++ks) {
                ah[ks] = *(const s8v*)(&hs[(mt*16 + l15)*SH + ks*32 + quad*8]);
                al[ks] = *(const s8v*)(&hl[(mt*16 + l15)*SH + ks*32 + quad*8]);
            }
            f4v c = {0.f,0.f,0.f,0.f};
            #pragma unroll
            for (int ks = 0; ks < 4; ++ks) c = MFMA16(ah[ks], bh[ks], c);
            #pragma unroll
            for (int ks = 0; ks < 4; ++ks) c = MFMA16(ah[ks], bl[ks], c);
            #pragma unroll
            for (int ks = 0; ks < 4; ++ks) c = MFMA16(al[ks], bh[ks], c);
            #pragma unroll
            for (int rg = 0; rg < 4; ++rg)
                xb[(mt*16 + quad*4 + rg)*132 + cg] += c[rg];
        }
        __syncthreads();
        // --- LN2 (hi only), 2 passes ---
        #pragma unroll
        for (int pp = 0; pp < 2; ++pp) {
            const int row = pp*64 + myrow;
            float v[16];
            #pragma unroll
            for (int j = 0; j < 4; ++j)
                *(float4*)&v[j*4] = *(const float4*)&xb[row*132 + lp*16 + j*4];
            float s = 0.f, q = 0.f;
            #pragma unroll
            for (int i = 0; i < 16; ++i) { s += v[i]; q += v[i]*v[i]; }
            #pragma unroll
            for (int o = 8; o < 64; o <<= 1) { s += __shfl_xor(s, o); q += __shfl_xor(q, o); }
            const float m  = s * (1.0f/128.0f);
            const float rs = rsqrtf(q * (1.0f/128.0f) - m*m + 1e-5f);
            unsigned short hi16[16];
            #pragma unroll
            for (int j = 0; j < 4; ++j) {
                const float4 g = *(const float4*)(g2a + lp*16 + j*4);
                const float4 b = *(const float4*)(b2a + lp*16 + j*4);
                hi16[j*4+0] = f2bf((v[j*4+0]-m)*rs*g.x + b.x);
                hi16[j*4+1] = f2bf((v[j*4+1]-m)*rs*g.y + b.y);
                hi16[j*4+2] = f2bf((v[j*4+2]-m)*rs*g.z + b.z);
                hi16[j*4+3] = f2bf((v[j*4+3]-m)*rs*g.w + b.w);
            }
            #pragma unroll
            for (int j = 0; j < 2; ++j)
                *(s8v*)&hs[row*SH + lp*16 + j*8] = *(const s8v*)&hi16[j*8];
        }
        __syncthreads();
        // --- FF: 4 quarters; w1 from registers, w2 in-loop ---
        f4v dx2[8];
        #pragma unroll
        for (int i = 0; i < 8; ++i) dx2[i] = (f4v){0.f,0.f,0.f,0.f};
        #pragma unroll
        for (int qf = 0; qf < 4; ++qf) {
            const float bias = b1r[qf];
            #pragma unroll
            for (int mt = 0; mt < 8; ++mt) {
                s8v af[4];
                #pragma unroll
                for (int ks = 0; ks < 4; ++ks)
                    af[ks] = *(const s8v*)(&hs[(mt*16 + l15)*SH + ks*32 + quad*8]);
                f4v c = {0.f,0.f,0.f,0.f};
                #pragma unroll
                for (int ks = 0; ks < 4; ++ks) c = MFMA16(af[ks], wa[qf][ks], c);
                #pragma unroll
                for (int rg = 0; rg < 4; ++rg) {
                    float vv = c[rg] + bias;
                    vv = vv > 0.f ? vv : 0.f;
                    fbuf[(mt*16 + quad*4 + rg)*SH + cg] = f2bf(vv);
                }
            }
            __syncthreads();
            s8v wb[4];
            #pragma unroll
            for (int ks = 0; ks < 4; ++ks)
                wb[ks] = *(const s8v*)(w2p + cg*FFD + qf*128 + ks*32 + quad*8);
            #pragma unroll
            for (int mt = 0; mt < 8; ++mt) {
                s8v af[4];
                #pragma unroll
                for (int ks = 0; ks < 4; ++ks)
                    af[ks] = *(const s8v*)(&fbuf[(mt*16 + l15)*SH + ks*32 + quad*8]);
                f4v c = dx2[mt];
                #pragma unroll
                for (int ks = 0; ks < 4; ++ks) c = MFMA16(af[ks], wb[ks], c);
                dx2[mt] = c;
            }
            __syncthreads();
        }
        // --- epilogue: xb += dx2 + b2 ---
        {
            const float bias = fb2[cg];
            #pragma unroll
            for (int mt = 0; mt < 8; ++mt)
                #pragma unroll
                for (int rg = 0; rg < 4; ++rg)
                    xb[(mt*16 + quad*4 + rg)*132 + cg] += dx2[mt][rg] + bias;
        }
        __syncthreads();
        // --- coalesced non-temporal store (in-place safe) ---
        #pragma unroll
        for (int i = 0; i < 8; ++i) {
            const int idx = tid + i*512;
            const int r = idx >> 5, c = (idx & 31)*4;
            ntstore4(xout + (r0 + r)*DIM + c, *(const f4v*)&xb[r*132 + c]);
        }
        __syncthreads();
    }
}

// ---------------------------------------------------------------------------
// Final: out = x @ out_w + out_b  (split-x, in-place safe on d_out).
// Owp fragments hoisted out of the chunk loop.
// ---------------------------------------------------------------------------
#define CHUNKF 64
#define NCHUNKF 4
static_assert((long)NBLK * CHUNKF * NCHUNKF == NROWS, "kF grid mismatch");

__global__ __launch_bounds__(256, 2)
void kF(const float* __restrict__ x, const unsigned short* __restrict__ Owp,
        const float* __restrict__ ob, float* __restrict__ out)
{
    __shared__ unsigned short hh[64*SH];
    __shared__ unsigned short hl[64*SH];
    __shared__ float          xb[64*132];
    const int tid  = threadIdx.x;
    const int quad = (tid & 63) >> 4, l15 = tid & 15;
    const int wv_  = tid >> 6;

    s8v bf[2][4];
    #pragma unroll
    for (int nt = 0; nt < 2; ++nt)
        #pragma unroll
        for (int ks = 0; ks < 4; ++ks)
            bf[nt][ks] = *(const s8v*)(Owp + (wv_*32 + nt*16 + l15)*DIM + ks*32 + quad*8);

    for (int ch = 0; ch < NCHUNKF; ++ch) {
        const size_t r0 = ((size_t)blockIdx.x*NCHUNKF + ch)*CHUNKF;
        #pragma unroll
        for (int i = 0; i < 8; ++i) {
            const int idx = tid + i*256;
            const int r = idx >> 5, c = (idx & 31)*4;
            const f4v v = ntload4(x + (r0 + r)*DIM + c);
            const unsigned short h0 = f2bf(v[0]), h1 = f2bf(v[1]),
                                 h2 = f2bf(v[2]), h3 = f2bf(v[3]);
            u16x4 w4 = { h0, h1, h2, h3 };
            u16x4 l4 = { f2bf(v[0] - bf2f(h0)), f2bf(v[1] - bf2f(h1)),
                         f2bf(v[2] - bf2f(h2)), f2bf(v[3] - bf2f(h3)) };
            *(u16x4*)&hh[r*SH + c] = w4;
            *(u16x4*)&hl[r*SH + c] = l4;
        }
        __syncthreads();
        #pragma unroll
        for (int mt = 0; mt < 4; ++mt) {
            s8v ah[4], al[4];
            #pragma unroll
            for (int ks = 0; ks < 4; ++ks) {
                ah[ks] = *(const s8v*)(&hh[(mt*16 + l15)*SH + ks*32 + quad*8]);
                al[ks] = *(const s8v*)(&hl[(mt*16 + l15)*SH + ks*32 + quad*8]);
            }
            #pragma unroll
            for (int nt = 0; nt < 2; ++nt) {
                f4v c = {0.f,0.f,0.f,0.f};
                #pragma unroll
                for (int ks = 0; ks < 4; ++ks) c = MFMA16(ah[ks], bf[nt][ks], c);
                #pragma unroll
                for (int ks = 0; ks < 4; ++ks) c = MFMA16(al[ks], bf[nt][ks], c);
                const int cg = wv_*32 + nt*16 + l15;
                const float bias = ob[cg];
                #pragma unroll
                for (int rg = 0; rg < 4; ++rg)
                    xb[(mt*16 + quad*4 + rg)*132 + cg] = c[rg] + bias;
            }
        }
        __syncthreads();
        #pragma unroll
        for (int i = 0; i < 8; ++i) {
            const int idx = tid + i*256;
            const int r = idx >> 5, c = (idx & 31)*4;
            ntstore4(out + (r0 + r)*DIM + c, *(const f4v*)&xb[r*132 + c]);
        }
        __syncthreads();
    }
}

// Pack weights to bf16, transposed to B-operand-friendly [n][k] layout.
__global__ void kPack(const float* __restrict__ Kw, const float* __restrict__ Vw,
                      const float* __restrict__ Ow, const float* __restrict__ w1,
                      const float* __restrict__ w2,
                      unsigned short* __restrict__ Kwp, unsigned short* __restrict__ Vwp,
                      unsigned short* __restrict__ Owp, unsigned short* __restrict__ w1p,
                      unsigned short* __restrict__ w2p)
{
    const int t = blockIdx.x*256 + threadIdx.x;  // 147456 total
    if (t < 16384) {
        const int n = t >> 7, k = t & 127;
        Kwp[t] = f2bf(Kw[k*128 + n]);
        Vwp[t] = f2bf(Vw[k*128 + n]);
        Owp[t] = f2bf(Ow[k*128 + n]);
    } else if (t < 16384 + 65536) {
        const int u = t - 16384;
        const int n = u >> 7, k = u & 127;      // w1: [128][512] -> w1p[n<512][k<128]
        w1p[u] = f2bf(w1[k*FFD + n]);
    } else {
        const int u = t - 16384 - 65536;
        const int n = u >> 9, k = u & 511;      // w2: [512][128] -> w2p[n<128][k<512]
        w2p[u] = f2bf(w2[k*DIM + n]);
    }
}

extern "C" void kernel_launch(void* const* d_in, const int* in_sizes, int n_in,
                              void* d_out, int out_size, void* d_ws, size_t ws_size,
                              hipStream_t stream)
{
    (void)in_sizes; (void)n_in; (void)out_size; (void)ws_size;
    const float* x_in = (const float*)d_in[0];
    const float* Kw   = (const float*)d_in[1];
    const float* Qw   = (const float*)d_in[2];
    const float* Vw   = (const float*)d_in[3];
    const float* ln1g = (const float*)d_in[4];
    const float* ln1b = (const float*)d_in[5];
    const float* ln2g = (const float*)d_in[6];
    const float* ln2b = (const float*)d_in[7];
    const float* w1   = (const float*)d_in[8];
    const float* b1   = (const float*)d_in[9];
    const float* w2   = (const float*)d_in[10];
    const float* b2   = (const float*)d_in[11];
    const float* Ow   = (const float*)d_in[12];
    const float* ob   = (const float*)d_in[13];

    // Workspace (~1.5 MiB single-copy layout).
    char* p = (char*)d_ws;
    float* slots        = (float*)p;          p += (size_t)NSLOT*16384*4;
    float* ktv          = (float*)p;          p += 16384*4;
    unsigned short* Kwp = (unsigned short*)p; p += 16384*2;
    unsigned short* Vwp = (unsigned short*)p; p += 16384*2;
    unsigned short* Owp = (unsigned short*)p; p += 16384*2;
    unsigned short* w1p = (unsigned short*)p; p += 65536*2;
    unsigned short* w2p = (unsigned short*)p; p += 65536*2;
    unsigned short* Mp  = (unsigned short*)p; p += 16384*2;
    unsigned short* Ml  = (unsigned short*)p; p += 16384*2;

    float* X = (float*)d_out;   // working buffer == output buffer

    kPack<<<576, 256, 0, stream>>>(Kw, Vw, Ow, w1, w2, Kwp, Vwp, Owp, w1p, w2p);

    const float* src = x_in;
    for (int t = 0; t < TSTEPS; ++t) {
        (void)hipMemsetAsync(slots, 0, (size_t)NSLOT*16384*4, stream);
        kA<<<NBLK, 512, 0, stream>>>(src, Kwp, Vwp, ln1g, ln1b, slots);
        kReduce<<<64, 256, 0, stream>>>(slots, ktv);
        kBuildM<<<64, 256, 0, stream>>>(Qw, ktv, Mp, Ml);
        kB<<<NBLK, 512, 0, stream>>>(src, X, Mp, Ml, ln1g, ln1b, ln2g, ln2b,
                                     w1p, b1, w2p, b2);
        src = X;
    }
    kF<<<NBLK, 256, 0, stream>>>(X, Owp, ob, (float*)d_out);
}